// Round 1
// baseline (9765.682 us; speedup 1.0000x reference)
//
#include <hip/hip_runtime.h>
#include <cstddef>

// Problem constants (reference: B,C,T = 8,256,8192; DILATIONS=(1,2,4); slope 0.1)
constexpr int Bn = 8;
constexpr int Cn = 256;
constexpr int Tn = 8192;
constexpr float SLOPE = 0.1f;

__device__ __forceinline__ float lrelu(float v) { return v > 0.f ? v : SLOPE * v; }

// ---------------------------------------------------------------------------
// Kernel 1: z = lrelu( WC*lrelu(x) + WP*xP + WF*xF + biases )
// where xP/xF are the pitch-dependent past/future gathers of lrelu(x).
// GEMM-shaped: M=64 o-tile x N=64 t-tile, K=256 in chunks of 16, 4x4/thread.
// ---------------------------------------------------------------------------
__global__ __launch_bounds__(256)
void k_gemm1(const float* __restrict__ x, const float* __restrict__ d,
             const float* __restrict__ WC, const float* __restrict__ bC,
             const float* __restrict__ WP, const float* __restrict__ bP,
             const float* __restrict__ WF, const float* __restrict__ bF,
             float dil, float* __restrict__ z)
{
    constexpr int TM = 64, TN = 64, KC = 16;
    const int b  = blockIdx.z;
    const int o0 = blockIdx.y * TM;
    const int t0 = blockIdx.x * TN;

    __shared__ float sWC[TM][KC], sWP[TM][KC], sWF[TM][KC];
    __shared__ float sXT[KC][TN + 1], sXP[KC][TN + 1], sXF[KC][TN + 1];
    __shared__ int   sTP[TN], sTF[TN];
    __shared__ float sVP[TN], sVF[TN];

    const int tid = threadIdx.x;

    // Gather indices for this t-tile (depend on (b,t) only).
    if (tid < TN) {
        int t = t0 + tid;
        float dv = d[(size_t)b * Tn + t] * dil;
        float tf = (float)t;
        int ip = (int)rintf(tf - dv);   // round-half-even matches jnp.round
        int iF = (int)rintf(tf + dv);
        sVP[tid] = (ip >= 0) ? 1.f : 0.f;
        sVF[tid] = (iF < Tn) ? 1.f : 0.f;
        sTP[tid] = min(max(ip, 0), Tn - 1);
        sTF[tid] = min(max(iF, 0), Tn - 1);
    }
    __syncthreads();

    float acc[4][4] = {};
    const int ty = tid >> 4;   // 0..15 : o = o0 + ty + 16*i
    const int tx = tid & 15;   // 0..15 : t = t0 + tx + 16*j

    const float* xb = x + (size_t)b * Cn * Tn;

    for (int c0 = 0; c0 < Cn; c0 += KC) {
        // Stage W tiles: 3 x (64x16)
        for (int l = tid; l < TM * KC; l += 256) {
            int oo = l / KC, cc = l % KC;
            int widx = (o0 + oo) * Cn + (c0 + cc);
            sWC[oo][cc] = WC[widx];
            sWP[oo][cc] = WP[widx];
            sWF[oo][cc] = WF[widx];
        }
        // Stage X tiles: xt coalesced, xP/xF gathered (near-monotone -> cache hits)
        for (int l = tid; l < KC * TN; l += 256) {
            int cc = l / TN, tt = l % TN;
            const float* xc = xb + (size_t)(c0 + cc) * Tn;
            sXT[cc][tt] = lrelu(xc[t0 + tt]);
            sXP[cc][tt] = lrelu(xc[sTP[tt]]) * sVP[tt];
            sXF[cc][tt] = lrelu(xc[sTF[tt]]) * sVF[tt];
        }
        __syncthreads();

        #pragma unroll
        for (int cc = 0; cc < KC; ++cc) {
            float wc[4], wp[4], wf[4], vt[4], vp[4], vf[4];
            #pragma unroll
            for (int i = 0; i < 4; ++i) {
                wc[i] = sWC[ty + 16 * i][cc];
                wp[i] = sWP[ty + 16 * i][cc];
                wf[i] = sWF[ty + 16 * i][cc];
            }
            #pragma unroll
            for (int j = 0; j < 4; ++j) {
                vt[j] = sXT[cc][tx + 16 * j];
                vp[j] = sXP[cc][tx + 16 * j];
                vf[j] = sXF[cc][tx + 16 * j];
            }
            #pragma unroll
            for (int i = 0; i < 4; ++i)
                #pragma unroll
                for (int j = 0; j < 4; ++j)
                    acc[i][j] += wc[i] * vt[j] + wp[i] * vp[j] + wf[i] * vf[j];
        }
        __syncthreads();
    }

    #pragma unroll
    for (int i = 0; i < 4; ++i) {
        int o = o0 + ty + 16 * i;
        float bias = bC[o] + bP[o] + bF[o];
        #pragma unroll
        for (int j = 0; j < 4; ++j) {
            int t = t0 + tx + 16 * j;
            z[((size_t)b * Cn + o) * Tn + t] = lrelu(acc[i][j] + bias);
        }
    }
}

// ---------------------------------------------------------------------------
// Kernel 2: out = conv3(z, WA) + bA + xres   (residual add, in-place safe)
// ---------------------------------------------------------------------------
__global__ __launch_bounds__(256)
void k_conv3(const float* __restrict__ z, const float* __restrict__ WA,
             const float* __restrict__ bA, const float* __restrict__ xres,
             float* __restrict__ out)
{
    constexpr int TM = 64, TN = 64, KC = 16;
    const int b  = blockIdx.z;
    const int o0 = blockIdx.y * TM;
    const int t0 = blockIdx.x * TN;

    __shared__ float sW[TM][KC][3];       // 12 KB
    __shared__ float sZ[KC][TN + 2 + 1];  // halo +-1, pad

    const int tid = threadIdx.x;
    const int ty = tid >> 4, tx = tid & 15;
    float acc[4][4] = {};
    const float* zb = z + (size_t)b * Cn * Tn;

    for (int c0 = 0; c0 < Cn; c0 += KC) {
        for (int l = tid; l < TM * KC * 3; l += 256) {
            int oo = l / (KC * 3);
            int r  = l % (KC * 3);
            int cc = r / 3, k = r % 3;
            sW[oo][cc][k] = WA[((size_t)(o0 + oo) * Cn + (c0 + cc)) * 3 + k];
        }
        for (int l = tid; l < KC * (TN + 2); l += 256) {
            int cc = l / (TN + 2), tt = l % (TN + 2);
            int t = t0 + tt - 1;
            sZ[cc][tt] = (t >= 0 && t < Tn) ? zb[(size_t)(c0 + cc) * Tn + t] : 0.f;
        }
        __syncthreads();

        #pragma unroll
        for (int cc = 0; cc < KC; ++cc) {
            float w0[4], w1[4], w2[4];
            #pragma unroll
            for (int i = 0; i < 4; ++i) {
                w0[i] = sW[ty + 16 * i][cc][0];
                w1[i] = sW[ty + 16 * i][cc][1];
                w2[i] = sW[ty + 16 * i][cc][2];
            }
            #pragma unroll
            for (int j = 0; j < 4; ++j) {
                int tt = tx + 16 * j;
                float zm = sZ[cc][tt];
                float z0 = sZ[cc][tt + 1];
                float zp = sZ[cc][tt + 2];
                #pragma unroll
                for (int i = 0; i < 4; ++i)
                    acc[i][j] += w0[i] * zm + w1[i] * z0 + w2[i] * zp;
            }
        }
        __syncthreads();
    }

    #pragma unroll
    for (int i = 0; i < 4; ++i) {
        int o = o0 + ty + 16 * i;
        float bias = bA[o];
        #pragma unroll
        for (int j = 0; j < 4; ++j) {
            int t = t0 + tx + 16 * j;
            size_t idx = ((size_t)b * Cn + o) * Tn + t;
            out[idx] = acc[i][j] + bias + xres[idx];   // read-then-write same elem: in-place safe
        }
    }
}

extern "C" void kernel_launch(void* const* d_in, const int* in_sizes, int n_in,
                              void* d_out, int out_size, void* d_ws, size_t ws_size,
                              hipStream_t stream)
{
    const float* x  = (const float*)d_in[0];
    const float* d  = (const float*)d_in[1];
    const float* WC = (const float*)d_in[2];
    const float* bC = (const float*)d_in[3];
    const float* WP = (const float*)d_in[4];
    const float* bP = (const float*)d_in[5];
    const float* WF = (const float*)d_in[6];
    const float* bF = (const float*)d_in[7];
    const float* WA = (const float*)d_in[8];
    const float* bA = (const float*)d_in[9];

    float* out = (float*)d_out;
    float* z   = (float*)d_ws;   // 64 MB intermediate, fully rewritten each layer

    dim3 grid(Tn / 64, Cn / 64, Bn);   // 128 x 4 x 8 = 4096 blocks
    dim3 block(256);

    const float dils[3] = {1.f, 2.f, 4.f};
    const float* xcur = x;
    for (int i = 0; i < 3; ++i) {
        k_gemm1<<<grid, block, 0, stream>>>(
            xcur, d,
            WC + (size_t)i * Cn * Cn, bC + (size_t)i * Cn,
            WP + (size_t)i * Cn * Cn, bP + (size_t)i * Cn,
            WF + (size_t)i * Cn * Cn, bF + (size_t)i * Cn,
            dils[i], z);
        k_conv3<<<grid, block, 0, stream>>>(
            z, WA + (size_t)i * Cn * Cn * 3, bA + (size_t)i * Cn,
            xcur, out);
        xcur = out;   // layers 1,2: residual read/write in-place (element-exact)
    }
}

// Round 2
// 438.486 us; speedup vs baseline: 22.2714x; 22.2714x over previous
//
#include <hip/hip_runtime.h>
#include <hip/hip_bf16.h>
#include <cstddef>
#include <cstdint>

constexpr int Bn = 8, Cn = 256, Tn = 8192;
constexpr int NL = 3;          // layers / dilations (1,2,4)
constexpr int Kc = 768;        // K for both fused GEMMs (3*256)
constexpr float SLOPE = 0.1f;

typedef unsigned short u16;
using bf8   = __attribute__((ext_vector_type(8))) short;  // 8 bf16 = 4 VGPRs
using f32x4 = __attribute__((ext_vector_type(4))) float;

__device__ __forceinline__ float lrelu(float v) { return v > 0.f ? v : SLOPE * v; }
__device__ __forceinline__ u16 f2bf(float f) {
    __hip_bfloat16 h = __float2bfloat16(f);
    return *reinterpret_cast<u16*>(&h);
}

// ---------------------------------------------------------------------------
// Weight prep (once per launch): bf16 Wcat[l][o][s*256+c] from WC/WP/WF,
// bf16 WAp[l][o][tap*256+c] from WA[l][o][c][tap], bSum = bC+bP+bF.
// ---------------------------------------------------------------------------
__global__ __launch_bounds__(256)
void k_wprep(const float* __restrict__ WC, const float* __restrict__ WP,
             const float* __restrict__ WF, const float* __restrict__ WA,
             const float* __restrict__ bC, const float* __restrict__ bP,
             const float* __restrict__ bF,
             u16* __restrict__ Wcat, u16* __restrict__ WAp, float* __restrict__ bSum)
{
    const int n1 = NL * Cn * Kc;
    for (int i = blockIdx.x * blockDim.x + threadIdx.x; i < n1;
         i += gridDim.x * blockDim.x) {
        int c = i % Cn;
        int s = (i / Cn) % 3;
        int o = (i / (3 * Cn)) % Cn;
        int l = i / (3 * Cn * Cn);
        size_t src = ((size_t)l * Cn + o) * Cn + c;
        float wc = (s == 0) ? WC[src] : (s == 1) ? WP[src] : WF[src];
        Wcat[i] = f2bf(wc);
        // WAp: k index = tap*256 + c, source WA[l][o][c][tap]
        WAp[i] = f2bf(WA[src * 3 + s]);
    }
    for (int i = blockIdx.x * blockDim.x + threadIdx.x; i < NL * Cn;
         i += gridDim.x * blockDim.x)
        bSum[i] = bC[i] + bP[i] + bF[i];
}

// ---------------------------------------------------------------------------
// Per-layer prep: xT[b][t][c] = bf16(lrelu(x[b][c][t]))  (transpose via LDS)
// ---------------------------------------------------------------------------
__global__ __launch_bounds__(256)
void k_prep(const float* __restrict__ x, u16* __restrict__ xT)
{
    __shared__ float s[64][65];
    const int b = blockIdx.z, c0 = blockIdx.y * 64, t0 = blockIdx.x * 64;
    const int tid = threadIdx.x;
    const float* xb = x + ((size_t)b * Cn + c0) * Tn + t0;

    int tt = tid & 63, c4 = tid >> 6;
    for (int cc = c4; cc < 64; cc += 4)
        s[cc][tt] = xb[(size_t)cc * Tn + tt];
    __syncthreads();

    int ccS = tid & 63, t4 = tid >> 6;
    u16* xTb = xT + ((size_t)b * Tn + t0) * Cn + c0;
    for (int t2 = t4; t2 < 64; t2 += 4)
        xTb[(size_t)t2 * Cn + ccS] = f2bf(lrelu(s[ccS][t2]));
}

// ---------------------------------------------------------------------------
// GEMM1: zT[b][t][o] = bf16(lrelu( sum_k Xcat[t][k] * Wcat[o][k] + bSum[o] ))
//   Xcat segments: 0 = xt (row t), 1 = xP (row idxP or zero), 2 = xF.
//   MFMA: A = X (m=t), B = W (n=o). 128x128 tile, 4 waves of 64x64.
// ---------------------------------------------------------------------------
__global__ __launch_bounds__(256)
void k_gemm1(const u16* __restrict__ xT, const float* __restrict__ d,
             const u16* __restrict__ Wl, const float* __restrict__ bS,
             float dil, u16* __restrict__ zT)
{
    __shared__ u16 sX[128 * 32];
    __shared__ u16 sW[128 * 32];
    __shared__ int sRow[3][128];

    const int tid = threadIdx.x;
    const int b = blockIdx.z;
    const int t0 = blockIdx.x * 128;
    const int o0 = blockIdx.y * 128;

    if (tid < 128) {
        int t = t0 + tid;
        float dv = d[(size_t)b * Tn + t] * dil;
        int ip = (int)rintf((float)t - dv);   // round-half-even == jnp.round
        int iF = (int)rintf((float)t + dv);
        sRow[0][tid] = t;
        sRow[1][tid] = (ip >= 0) ? ip : -1;   // ip <= t < Tn always
        sRow[2][tid] = (iF < Tn) ? iF : -1;   // iF >= t >= 0 always
    }
    __syncthreads();

    const int srow = tid >> 2;            // 0..63 (handles rows srow, srow+64)
    const int schunk = (tid & 3) * 8;     // halfword offset within 32
    int rA0[3], rA1[3];
    #pragma unroll
    for (int s = 0; s < 3; ++s) { rA0[s] = sRow[s][srow]; rA1[s] = sRow[s][srow + 64]; }

    const int lane = tid & 63, wv = tid >> 6;
    const int wm = (wv & 1) * 64;   // t-half
    const int wn = (wv >> 1) * 64;  // o-half
    const int lr = lane & 15, quad = lane >> 4;

    f32x4 acc[4][4] = {};
    const u16* xTb = xT + (size_t)b * Tn * Cn;

    for (int kg = 0; kg < Kc; kg += 32) {
        const int seg = kg >> 8, c0 = kg & 255;
        // global loads to registers (overlap with previous MFMA work)
        const u16* wsrc = Wl + (size_t)(o0 + srow) * Kc + kg + schunk;
        uint4 w0 = *(const uint4*)wsrc;
        uint4 w1 = *(const uint4*)(wsrc + (size_t)64 * Kc);
        uint4 x0 = {0, 0, 0, 0}, x1 = {0, 0, 0, 0};
        int r0 = rA0[seg], r1 = rA1[seg];
        if (r0 >= 0) x0 = *(const uint4*)(xTb + (size_t)r0 * Cn + c0 + schunk);
        if (r1 >= 0) x1 = *(const uint4*)(xTb + (size_t)r1 * Cn + c0 + schunk);
        __syncthreads();
        *(uint4*)(sW + srow * 32 + schunk) = w0;
        *(uint4*)(sW + (srow + 64) * 32 + schunk) = w1;
        *(uint4*)(sX + srow * 32 + schunk) = x0;
        *(uint4*)(sX + (srow + 64) * 32 + schunk) = x1;
        __syncthreads();

        bf8 af[4], bg[4];
        #pragma unroll
        for (int mi = 0; mi < 4; ++mi)
            af[mi] = *(const bf8*)(sX + (wm + mi * 16 + lr) * 32 + quad * 8);
        #pragma unroll
        for (int ni = 0; ni < 4; ++ni)
            bg[ni] = *(const bf8*)(sW + (wn + ni * 16 + lr) * 32 + quad * 8);
        #pragma unroll
        for (int mi = 0; mi < 4; ++mi)
            #pragma unroll
            for (int ni = 0; ni < 4; ++ni)
                acc[mi][ni] = __builtin_amdgcn_mfma_f32_16x16x32_bf16(
                    af[mi], bg[ni], acc[mi][ni], 0, 0, 0);
    }

    // epilogue: D row = m = t (quad*4+r), col = n = o (lr)
    float bias[4];
    #pragma unroll
    for (int ni = 0; ni < 4; ++ni) bias[ni] = bS[o0 + wn + ni * 16 + lr];
    u16* zTb = zT + (size_t)b * Tn * Cn;
    #pragma unroll
    for (int mi = 0; mi < 4; ++mi)
        #pragma unroll
        for (int r = 0; r < 4; ++r) {
            int t = t0 + wm + mi * 16 + quad * 4 + r;
            u16* row = zTb + (size_t)t * Cn + o0 + wn;
            #pragma unroll
            for (int ni = 0; ni < 4; ++ni)
                row[ni * 16 + lr] = f2bf(lrelu(acc[mi][ni][r] + bias[ni]));
        }
}

// ---------------------------------------------------------------------------
// GEMM2 (conv3 + residual): out[b][o][t] = sum_{tap,c} WAp[o][tap*256+c] *
//   zT[t+tap-1][c]  + bA[o] + xres[b][o][t]
//   MFMA: A = W (m=o), B = Z (n=t). Same LDS layouts as gemm1.
// ---------------------------------------------------------------------------
__global__ __launch_bounds__(256)
void k_gemm2(const u16* __restrict__ zT, const u16* __restrict__ WAl,
             const float* __restrict__ bA, const float* __restrict__ xres,
             float* __restrict__ out)
{
    __shared__ u16 sZ[128 * 32];
    __shared__ u16 sW[128 * 32];

    const int tid = threadIdx.x;
    const int b = blockIdx.z;
    const int t0 = blockIdx.x * 128;
    const int o0 = blockIdx.y * 128;

    const int srow = tid >> 2;
    const int schunk = (tid & 3) * 8;
    const int lane = tid & 63, wv = tid >> 6;
    const int wo = (wv & 1) * 64;   // o-half (m)
    const int wt = (wv >> 1) * 64;  // t-half (n)
    const int lr = lane & 15, quad = lane >> 4;

    f32x4 acc[4][4] = {};
    const u16* zTb = zT + (size_t)b * Tn * Cn;

    for (int kg = 0; kg < Kc; kg += 32) {
        const int tap = kg >> 8, c0 = kg & 255;
        const u16* wsrc = WAl + (size_t)(o0 + srow) * Kc + kg + schunk;
        uint4 w0 = *(const uint4*)wsrc;
        uint4 w1 = *(const uint4*)(wsrc + (size_t)64 * Kc);
        int r0 = t0 + srow + tap - 1;
        int r1 = r0 + 64;
        uint4 z0 = {0, 0, 0, 0}, z1 = {0, 0, 0, 0};
        if (r0 >= 0 && r0 < Tn) z0 = *(const uint4*)(zTb + (size_t)r0 * Cn + c0 + schunk);
        if (r1 >= 0 && r1 < Tn) z1 = *(const uint4*)(zTb + (size_t)r1 * Cn + c0 + schunk);
        __syncthreads();
        *(uint4*)(sW + srow * 32 + schunk) = w0;
        *(uint4*)(sW + (srow + 64) * 32 + schunk) = w1;
        *(uint4*)(sZ + srow * 32 + schunk) = z0;
        *(uint4*)(sZ + (srow + 64) * 32 + schunk) = z1;
        __syncthreads();

        bf8 af[4], bg[4];
        #pragma unroll
        for (int mi = 0; mi < 4; ++mi)
            af[mi] = *(const bf8*)(sW + (wo + mi * 16 + lr) * 32 + quad * 8);
        #pragma unroll
        for (int ni = 0; ni < 4; ++ni)
            bg[ni] = *(const bf8*)(sZ + (wt + ni * 16 + lr) * 32 + quad * 8);
        #pragma unroll
        for (int mi = 0; mi < 4; ++mi)
            #pragma unroll
            for (int ni = 0; ni < 4; ++ni)
                acc[mi][ni] = __builtin_amdgcn_mfma_f32_16x16x32_bf16(
                    af[mi], bg[ni], acc[mi][ni], 0, 0, 0);
    }

    // epilogue: row = m = o (quad*4+r), col = n = t (lr). Coalesced fp32 stores.
    #pragma unroll
    for (int mi = 0; mi < 4; ++mi)
        #pragma unroll
        for (int r = 0; r < 4; ++r) {
            int o = o0 + wo + mi * 16 + quad * 4 + r;
            float bv = bA[o];
            size_t base = ((size_t)b * Cn + o) * Tn + t0 + wt;
            #pragma unroll
            for (int ni = 0; ni < 4; ++ni) {
                size_t idx = base + ni * 16 + lr;
                out[idx] = acc[mi][ni][r] + bv + xres[idx];
            }
        }
}

extern "C" void kernel_launch(void* const* d_in, const int* in_sizes, int n_in,
                              void* d_out, int out_size, void* d_ws, size_t ws_size,
                              hipStream_t stream)
{
    const float* x  = (const float*)d_in[0];
    const float* d  = (const float*)d_in[1];
    const float* WC = (const float*)d_in[2];
    const float* bC = (const float*)d_in[3];
    const float* WP = (const float*)d_in[4];
    const float* bP = (const float*)d_in[5];
    const float* WF = (const float*)d_in[6];
    const float* bF = (const float*)d_in[7];
    const float* WA = (const float*)d_in[8];
    const float* bA = (const float*)d_in[9];
    float* out = (float*)d_out;

    // workspace layout (bytes):
    char* ws = (char*)d_ws;
    u16*   xT   = (u16*)(ws);                                   // 32 MiB
    u16*   zT   = (u16*)(ws + (size_t)Bn * Tn * Cn * 2);        // 32 MiB
    u16*   Wcat = (u16*)(ws + (size_t)2 * Bn * Tn * Cn * 2);    // 1.125 MiB
    u16*   WAp  = Wcat + (size_t)NL * Cn * Kc;                  // 1.125 MiB
    float* bSum = (float*)(WAp + (size_t)NL * Cn * Kc);         // 3 KiB

    k_wprep<<<dim3(1024), dim3(256), 0, stream>>>(WC, WP, WF, WA, bC, bP, bF,
                                                  Wcat, WAp, bSum);

    dim3 gP(Tn / 64, Cn / 64, Bn);      // prep: 128 x 4 x 8
    dim3 gG(Tn / 128, Cn / 128, Bn);    // gemms: 64 x 2 x 8
    dim3 blk(256);

    const float dils[NL] = {1.f, 2.f, 4.f};
    const float* xcur = x;
    for (int i = 0; i < NL; ++i) {
        k_prep<<<gP, blk, 0, stream>>>(xcur, xT);
        k_gemm1<<<gG, blk, 0, stream>>>(xT, d,
                                        Wcat + (size_t)i * Cn * Kc,
                                        bSum + (size_t)i * Cn,
                                        dils[i], zT);
        k_gemm2<<<gG, blk, 0, stream>>>(zT,
                                        WAp + (size_t)i * Cn * Kc,
                                        bA + (size_t)i * Cn,
                                        xcur, out);
        xcur = out;   // residual read-then-write same element: in-place safe
    }
}

// Round 4
// 418.345 us; speedup vs baseline: 23.3436x; 1.0481x over previous
//
#include <hip/hip_runtime.h>
#include <hip/hip_bf16.h>
#include <cstddef>
#include <cstdint>

constexpr int Bn = 8, Cn = 256, Tn = 8192;
constexpr int NL = 3;          // layers / dilations (1,2,4)
constexpr int Kc = 768;        // K for both fused GEMMs (3*256)
constexpr float SLOPE = 0.1f;

typedef unsigned short u16;
using bf8   = __attribute__((ext_vector_type(8))) short;  // 8 bf16 = 4 VGPRs
using f32x4 = __attribute__((ext_vector_type(4))) float;

__device__ __forceinline__ float lrelu(float v) { return v > 0.f ? v : SLOPE * v; }
__device__ __forceinline__ u16 f2bf(float f) {
    __hip_bfloat16 h = __float2bfloat16(f);
    return *reinterpret_cast<u16*>(&h);
}

// async global->LDS, 16B per lane. LDS dest is wave-uniform base + lane*16,
// so it must be issued with ALL lanes active and lds_ptr == base + lane*16.
// Invalid rows are handled by redirecting the GLOBAL pointer to a zero row
// (per-lane global addresses are fine) — never by masking lanes off.
__device__ __forceinline__ void g2l16(const u16* g, u16* l) {
    __builtin_amdgcn_global_load_lds(
        (const __attribute__((address_space(1))) char*)g,
        (__attribute__((address_space(3))) char*)l, 16, 0, 0);
}

// ---------------------------------------------------------------------------
// Weight prep (once per launch): bf16 Wcat[l][o][s*256+c] from WC/WP/WF,
// bf16 WAp[l][o][tap*256+c] from WA[l][o][c][tap], bSum = bC+bP+bF.
// Also zero-fills the 256-u16 dummy row (ws is re-poisoned every launch).
// ---------------------------------------------------------------------------
__global__ __launch_bounds__(256)
void k_wprep(const float* __restrict__ WC, const float* __restrict__ WP,
             const float* __restrict__ WF, const float* __restrict__ WA,
             const float* __restrict__ bC, const float* __restrict__ bP,
             const float* __restrict__ bF,
             u16* __restrict__ Wcat, u16* __restrict__ WAp, float* __restrict__ bSum,
             u16* __restrict__ zrow)
{
    if (blockIdx.x == 0) zrow[threadIdx.x] = 0;   // 256 u16 zero row
    const int n1 = NL * Cn * Kc;
    for (int i = blockIdx.x * blockDim.x + threadIdx.x; i < n1;
         i += gridDim.x * blockDim.x) {
        int c = i % Cn;
        int s = (i / Cn) % 3;
        int o = (i / (3 * Cn)) % Cn;
        int l = i / (3 * Cn * Cn);
        size_t src = ((size_t)l * Cn + o) * Cn + c;
        float wc = (s == 0) ? WC[src] : (s == 1) ? WP[src] : WF[src];
        Wcat[i] = f2bf(wc);
        WAp[i] = f2bf(WA[src * 3 + s]);
    }
    for (int i = blockIdx.x * blockDim.x + threadIdx.x; i < NL * Cn;
         i += gridDim.x * blockDim.x)
        bSum[i] = bC[i] + bP[i] + bF[i];
}

// ---------------------------------------------------------------------------
// Layer-0 prep: xT[b][t][c] = bf16(lrelu(x[b][c][t]))  (transpose via LDS)
// ---------------------------------------------------------------------------
__global__ __launch_bounds__(256)
void k_prep(const float* __restrict__ x, u16* __restrict__ xT)
{
    __shared__ float s[64][65];
    const int b = blockIdx.z, c0 = blockIdx.y * 64, t0 = blockIdx.x * 64;
    const int tid = threadIdx.x;
    const float* xb = x + ((size_t)b * Cn + c0) * Tn + t0;

    int tt = tid & 63, c4 = tid >> 6;
    for (int cc = c4; cc < 64; cc += 4)
        s[cc][tt] = xb[(size_t)cc * Tn + tt];
    __syncthreads();

    int ccS = tid & 63, t4 = tid >> 6;
    u16* xTb = xT + ((size_t)b * Tn + t0) * Cn + c0;
    for (int t2 = t4; t2 < 64; t2 += 4)
        xTb[(size_t)t2 * Cn + ccS] = f2bf(lrelu(s[ccS][t2]));
}

// ---------------------------------------------------------------------------
// GEMM1: zT[b][t][o] = bf16(lrelu( sum_k Xcat[t][k]*Wcat[o][k] + bSum[o] ))
//   Xcat segs: 0 = row t, 1 = row idxP (or zrow), 2 = row idxF (or zrow).
//   A = X (m=t), B = W (n=o). 128x128 tile, 4 waves of 64x64, async staging.
// ---------------------------------------------------------------------------
__global__ __launch_bounds__(256)
void k_gemm1(const u16* __restrict__ xT, const float* __restrict__ d,
             const u16* __restrict__ Wl, const float* __restrict__ bS,
             float dil, u16* __restrict__ zT, const u16* __restrict__ zrow)
{
    __shared__ u16 sX[128 * 32];   // byte offset of (row srow, chunk schunk) = tid*16
    __shared__ u16 sW[128 * 32];
    __shared__ int sRow[3][128];

    const int tid = threadIdx.x;
    const int b = blockIdx.z;
    const int t0 = blockIdx.x * 128;
    const int o0 = blockIdx.y * 128;

    if (tid < 128) {
        int t = t0 + tid;
        float dv = d[(size_t)b * Tn + t] * dil;
        int ip = (int)rintf((float)t - dv);   // round-half-even == jnp.round
        int iF = (int)rintf((float)t + dv);
        sRow[0][tid] = t;
        sRow[1][tid] = (ip >= 0) ? ip : -1;
        sRow[2][tid] = (iF < Tn) ? iF : -1;
    }
    __syncthreads();

    const int srow = tid >> 2;            // 0..63 (rows srow, srow+64)
    const int schunk = (tid & 3) * 8;     // u16 offset within 32
    const u16* xTb = xT + (size_t)b * Tn * Cn;

    // precompute per-seg global row pointers; invalid rows -> zrow (zeros)
    const u16 *pr0[3], *pr1[3];
    #pragma unroll
    for (int s = 0; s < 3; ++s) {
        int r0 = sRow[s][srow], r1 = sRow[s][srow + 64];
        pr0[s] = (r0 >= 0) ? (xTb + (size_t)r0 * Cn + schunk) : (zrow + schunk);
        pr1[s] = (r1 >= 0) ? (xTb + (size_t)r1 * Cn + schunk) : (zrow + schunk);
    }

    const int lane = tid & 63, wv = tid >> 6;
    const int wm = (wv & 1) * 64;   // t-half
    const int wn = (wv >> 1) * 64;  // o-half
    const int lr = lane & 15, quad = lane >> 4;

    f32x4 acc[4][4] = {};

    #pragma unroll
    for (int seg = 0; seg < 3; ++seg) {
        const u16* xr0 = pr0[seg];
        const u16* xr1 = pr1[seg];
        const u16* wp0 = Wl + (size_t)(o0 + srow) * Kc + seg * 256 + schunk;
        const u16* wp1 = wp0 + (size_t)64 * Kc;
        #pragma unroll
        for (int kk = 0; kk < 256; kk += 32) {
            __syncthreads();   // prev iter's LDS reads done
            g2l16(wp0 + kk, sW + srow * 32 + schunk);
            g2l16(wp1 + kk, sW + (srow + 64) * 32 + schunk);
            g2l16(xr0 + kk, sX + srow * 32 + schunk);
            g2l16(xr1 + kk, sX + (srow + 64) * 32 + schunk);
            __syncthreads();   // vmcnt drained at barrier: LDS ready

            bf8 af[4], bg[4];
            #pragma unroll
            for (int mi = 0; mi < 4; ++mi)
                af[mi] = *(const bf8*)(sX + (wm + mi * 16 + lr) * 32 + quad * 8);
            #pragma unroll
            for (int ni = 0; ni < 4; ++ni)
                bg[ni] = *(const bf8*)(sW + (wn + ni * 16 + lr) * 32 + quad * 8);
            #pragma unroll
            for (int mi = 0; mi < 4; ++mi)
                #pragma unroll
                for (int ni = 0; ni < 4; ++ni)
                    acc[mi][ni] = __builtin_amdgcn_mfma_f32_16x16x32_bf16(
                        af[mi], bg[ni], acc[mi][ni], 0, 0, 0);
        }
    }

    // epilogue: D row = m = t (quad*4+r), col = n = o (lr)
    float bias[4];
    #pragma unroll
    for (int ni = 0; ni < 4; ++ni) bias[ni] = bS[o0 + wn + ni * 16 + lr];
    u16* zTb = zT + (size_t)b * Tn * Cn;
    #pragma unroll
    for (int mi = 0; mi < 4; ++mi)
        #pragma unroll
        for (int r = 0; r < 4; ++r) {
            int t = t0 + wm + mi * 16 + quad * 4 + r;
            u16* row = zTb + (size_t)t * Cn + o0 + wn;
            #pragma unroll
            for (int ni = 0; ni < 4; ++ni)
                row[ni * 16 + lr] = f2bf(lrelu(acc[mi][ni][r] + bias[ni]));
        }
}

// ---------------------------------------------------------------------------
// GEMM2 (conv3 + residual + fused next-layer prep):
//   out[b][o][t] = sum_{tap,c} WAp[o][tap*256+c]*zT[t+tap-1][c] + bA[o] + xres
//   if writeXT: xTn[b][t][o] = bf16(lrelu(out))  (per-wave LDS transpose)
//   A = W (m=o), B = Z (n=t). Halo rows out of [0,Tn) -> zrow.
// ---------------------------------------------------------------------------
__global__ __launch_bounds__(256)
void k_gemm2(const u16* __restrict__ zT, const u16* __restrict__ WAl,
             const float* __restrict__ bA, const float* __restrict__ xres,
             float* __restrict__ out, u16* __restrict__ xTn, int writeXT,
             const u16* __restrict__ zrow)
{
    __shared__ u16 smem[128 * 32 * 2];   // [sZ 4096 u16][sW 4096 u16]; reused by epilogue
    u16* sZ = smem;
    u16* sW = smem + 4096;

    const int tid = threadIdx.x;
    const int b = blockIdx.z;
    const int t0 = blockIdx.x * 128;
    const int o0 = blockIdx.y * 128;

    const int srow = tid >> 2;
    const int schunk = (tid & 3) * 8;
    const int lane = tid & 63, wv = tid >> 6;
    const int wo = (wv & 1) * 64;   // o-half (m)
    const int wt = (wv >> 1) * 64;  // t-half (n)
    const int lr = lane & 15, quad = lane >> 4;

    f32x4 acc[4][4] = {};
    const u16* zTb = zT + (size_t)b * Tn * Cn;

    #pragma unroll
    for (int tap = 0; tap < 3; ++tap) {
        const int r0 = t0 + srow + tap - 1;
        const int r1 = r0 + 64;
        const u16* zr0 = (r0 >= 0 && r0 < Tn) ? (zTb + (size_t)r0 * Cn + schunk)
                                              : (zrow + schunk);
        const u16* zr1 = (r1 >= 0 && r1 < Tn) ? (zTb + (size_t)r1 * Cn + schunk)
                                              : (zrow + schunk);
        const u16* wp0 = WAl + (size_t)(o0 + srow) * Kc + tap * 256 + schunk;
        const u16* wp1 = wp0 + (size_t)64 * Kc;
        #pragma unroll
        for (int kk = 0; kk < 256; kk += 32) {
            __syncthreads();
            g2l16(wp0 + kk, sW + srow * 32 + schunk);
            g2l16(wp1 + kk, sW + (srow + 64) * 32 + schunk);
            g2l16(zr0 + kk, sZ + srow * 32 + schunk);
            g2l16(zr1 + kk, sZ + (srow + 64) * 32 + schunk);
            __syncthreads();

            bf8 af[4], bg[4];
            #pragma unroll
            for (int mi = 0; mi < 4; ++mi)
                af[mi] = *(const bf8*)(sW + (wo + mi * 16 + lr) * 32 + quad * 8);
            #pragma unroll
            for (int ni = 0; ni < 4; ++ni)
                bg[ni] = *(const bf8*)(sZ + (wt + ni * 16 + lr) * 32 + quad * 8);
            #pragma unroll
            for (int mi = 0; mi < 4; ++mi)
                #pragma unroll
                for (int ni = 0; ni < 4; ++ni)
                    acc[mi][ni] = __builtin_amdgcn_mfma_f32_16x16x32_bf16(
                        af[mi], bg[ni], acc[mi][ni], 0, 0, 0);
        }
    }

    // bias per (mi,r): o = o0+wo+mi*16+quad*4+r
    float biasv[4][4];
    #pragma unroll
    for (int mi = 0; mi < 4; ++mi) {
        float4 bb = *(const float4*)(bA + o0 + wo + mi * 16 + quad * 4);
        biasv[mi][0] = bb.x; biasv[mi][1] = bb.y; biasv[mi][2] = bb.z; biasv[mi][3] = bb.w;
    }

    if (writeXT) {
        // per-wave 16t x 64o strips, padded rows (72 u16 = 144B) for alignment
        u16* strip = smem + wv * 1152;
        u16* xTb2 = xTn + (size_t)b * Tn * Cn;
        #pragma unroll
        for (int ni = 0; ni < 4; ++ni) {
            __syncthreads();   // staging/strip LDS free of readers
            #pragma unroll
            for (int mi = 0; mi < 4; ++mi) {
                ushort4 pk;
                #pragma unroll
                for (int r = 0; r < 4; ++r) {
                    int o = o0 + wo + mi * 16 + quad * 4 + r;
                    size_t idx = ((size_t)b * Cn + o) * Tn + t0 + wt + ni * 16 + lr;
                    float v = acc[mi][ni][r] + biasv[mi][r] + xres[idx];
                    out[idx] = v;
                    ((u16*)&pk)[r] = f2bf(lrelu(v));
                }
                *(ushort4*)(strip + lr * 72 + mi * 16 + quad * 4) = pk;
            }
            __syncthreads();   // strip writes visible
            #pragma unroll
            for (int it = 0; it < 2; ++it) {
                int tt = (lane >> 3) + it * 8;
                uint4 vv = *(const uint4*)(strip + tt * 72 + (lane & 7) * 8);
                *(uint4*)(xTb2 + (size_t)(t0 + wt + ni * 16 + tt) * Cn
                          + o0 + wo + (lane & 7) * 8) = vv;
            }
        }
    } else {
        #pragma unroll
        for (int mi = 0; mi < 4; ++mi)
            #pragma unroll
            for (int r = 0; r < 4; ++r) {
                int o = o0 + wo + mi * 16 + quad * 4 + r;
                size_t base = ((size_t)b * Cn + o) * Tn + t0 + wt;
                #pragma unroll
                for (int ni = 0; ni < 4; ++ni) {
                    size_t idx = base + ni * 16 + lr;
                    out[idx] = acc[mi][ni][r] + biasv[mi][r] + xres[idx];
                }
            }
    }
}

extern "C" void kernel_launch(void* const* d_in, const int* in_sizes, int n_in,
                              void* d_out, int out_size, void* d_ws, size_t ws_size,
                              hipStream_t stream)
{
    const float* x  = (const float*)d_in[0];
    const float* d  = (const float*)d_in[1];
    const float* WC = (const float*)d_in[2];
    const float* bC = (const float*)d_in[3];
    const float* WP = (const float*)d_in[4];
    const float* bP = (const float*)d_in[5];
    const float* WF = (const float*)d_in[6];
    const float* bF = (const float*)d_in[7];
    const float* WA = (const float*)d_in[8];
    const float* bA = (const float*)d_in[9];
    float* out = (float*)d_out;

    char* ws = (char*)d_ws;
    u16*   xT   = (u16*)(ws);                                   // 32 MiB
    u16*   zT   = (u16*)(ws + (size_t)Bn * Tn * Cn * 2);        // 32 MiB
    u16*   Wcat = (u16*)(ws + (size_t)2 * Bn * Tn * Cn * 2);    // 1.125 MiB
    u16*   WAp  = Wcat + (size_t)NL * Cn * Kc;                  // 1.125 MiB
    float* bSum = (float*)(WAp + (size_t)NL * Cn * Kc);         // 3 KiB
    u16*   zrow = (u16*)(bSum + NL * Cn);                       // 512 B zero row

    k_wprep<<<dim3(1024), dim3(256), 0, stream>>>(WC, WP, WF, WA, bC, bP, bF,
                                                  Wcat, WAp, bSum, zrow);

    dim3 gP(Tn / 64, Cn / 64, Bn);      // prep: 128 x 4 x 8
    dim3 gG(Tn / 128, Cn / 128, Bn);    // gemms: 64 x 2 x 8
    dim3 blk(256);

    k_prep<<<gP, blk, 0, stream>>>(x, xT);   // layer-0 input only

    const float dils[NL] = {1.f, 2.f, 4.f};
    const float* xcur = x;
    for (int i = 0; i < NL; ++i) {
        k_gemm1<<<gG, blk, 0, stream>>>(xT, d,
                                        Wcat + (size_t)i * Cn * Kc,
                                        bSum + (size_t)i * Cn,
                                        dils[i], zT, zrow);
        k_gemm2<<<gG, blk, 0, stream>>>(zT,
                                        WAp + (size_t)i * Cn * Kc,
                                        bA + (size_t)i * Cn,
                                        xcur, out, xT, (i < NL - 1) ? 1 : 0,
                                        zrow);
        xcur = out;   // residual read-then-write same element: in-place safe
    }
}

// Round 5
// 400.345 us; speedup vs baseline: 24.3932x; 1.0450x over previous
//
#include <hip/hip_runtime.h>
#include <hip/hip_bf16.h>
#include <cstddef>
#include <cstdint>

constexpr int Bn = 8, Cn = 256, Tn = 8192;
constexpr int NL = 3;          // layers / dilations (1,2,4)
constexpr int Kc = 768;        // K for both fused GEMMs (3*256)
constexpr float SLOPE = 0.1f;

typedef unsigned short u16;
using bf8   = __attribute__((ext_vector_type(8))) short;  // 8 bf16 = 4 VGPRs
using f32x4 = __attribute__((ext_vector_type(4))) float;

__device__ __forceinline__ float lrelu(float v) { return v > 0.f ? v : SLOPE * v; }
__device__ __forceinline__ u16 f2bf(float f) {
    __hip_bfloat16 h = __float2bfloat16(f);
    return *reinterpret_cast<u16*>(&h);
}

// async global->LDS, 16B per lane. LDS dest is wave-uniform base + lane*16:
// must be issued with ALL lanes active; invalid rows redirect the GLOBAL
// pointer to a zero row (per-lane global addresses are fine).
__device__ __forceinline__ void g2l16(const u16* g, u16* l) {
    __builtin_amdgcn_global_load_lds(
        (const __attribute__((address_space(1))) char*)g,
        (__attribute__((address_space(3))) char*)l, 16, 0, 0);
}

// ---------------------------------------------------------------------------
// Weight prep (once): bf16 Wcat[l][o][s*256+c] from WC/WP/WF,
// bf16 WAp[l][o][tap*256+c] from WA[l][o][c][tap], bSum = bC+bP+bF,
// zero dummy row (ws re-poisoned each launch).
// ---------------------------------------------------------------------------
__global__ __launch_bounds__(256)
void k_wprep(const float* __restrict__ WC, const float* __restrict__ WP,
             const float* __restrict__ WF, const float* __restrict__ WA,
             const float* __restrict__ bC, const float* __restrict__ bP,
             const float* __restrict__ bF,
             u16* __restrict__ Wcat, u16* __restrict__ WAp, float* __restrict__ bSum,
             u16* __restrict__ zrow)
{
    if (blockIdx.x == 0) zrow[threadIdx.x] = 0;
    const int n1 = NL * Cn * Kc;
    for (int i = blockIdx.x * blockDim.x + threadIdx.x; i < n1;
         i += gridDim.x * blockDim.x) {
        int c = i % Cn;
        int s = (i / Cn) % 3;
        int o = (i / (3 * Cn)) % Cn;
        int l = i / (3 * Cn * Cn);
        size_t src = ((size_t)l * Cn + o) * Cn + c;
        float wc = (s == 0) ? WC[src] : (s == 1) ? WP[src] : WF[src];
        Wcat[i] = f2bf(wc);
        WAp[i] = f2bf(WA[src * 3 + s]);
    }
    for (int i = blockIdx.x * blockDim.x + threadIdx.x; i < NL * Cn;
         i += gridDim.x * blockDim.x)
        bSum[i] = bC[i] + bP[i] + bF[i];
}

// ---------------------------------------------------------------------------
// Layer-0 prep: xT[b][t][c] = bf16(lrelu(x[b][c][t]))  (transpose via LDS)
// ---------------------------------------------------------------------------
__global__ __launch_bounds__(256)
void k_prep(const float* __restrict__ x, u16* __restrict__ xT)
{
    __shared__ float s[64][65];
    const int b = blockIdx.z, c0 = blockIdx.y * 64, t0 = blockIdx.x * 64;
    const int tid = threadIdx.x;
    const float* xb = x + ((size_t)b * Cn + c0) * Tn + t0;

    int tt = tid & 63, c4 = tid >> 6;
    for (int cc = c4; cc < 64; cc += 4)
        s[cc][tt] = xb[(size_t)cc * Tn + tt];
    __syncthreads();

    int ccS = tid & 63, t4 = tid >> 6;
    u16* xTb = xT + ((size_t)b * Tn + t0) * Cn + c0;
    for (int t2 = t4; t2 < 64; t2 += 4)
        xTb[(size_t)t2 * Cn + ccS] = f2bf(lrelu(s[ccS][t2]));
}

// ---------------------------------------------------------------------------
// GEMM1: zT[b][t][o] = bf16(lrelu( sum_k Xcat[t][k]*Wcat[o][k] + bSum[o] ))
//   A = X (m=t), B = W (n=o). 128x128 tile, 4 waves of 64x64.
//   Double-buffered async staging, ONE barrier per K-chunk:
//     iter k: barrier (drains chunk-k DMA, issued one full MFMA phase ago)
//             -> issue chunk-k+1 DMA into other buffer -> MFMA chunk k.
// ---------------------------------------------------------------------------
__global__ __launch_bounds__(256)
void k_gemm1(const u16* __restrict__ xT, const float* __restrict__ d,
             const u16* __restrict__ Wl, const float* __restrict__ bS,
             float dil, u16* __restrict__ zT, const u16* __restrict__ zrow)
{
    __shared__ u16 smem[4 * 4096];   // [sX0][sX1][sW0][sW1], 8 KB each
    __shared__ int sRow[3][128];

    const int tid = threadIdx.x;
    const int b = blockIdx.z;
    const int t0 = blockIdx.x * 128;
    const int o0 = blockIdx.y * 128;

    if (tid < 128) {
        int t = t0 + tid;
        float dv = d[(size_t)b * Tn + t] * dil;
        int ip = (int)rintf((float)t - dv);   // round-half-even == jnp.round
        int iF = (int)rintf((float)t + dv);
        sRow[0][tid] = t;
        sRow[1][tid] = (ip >= 0) ? ip : -1;
        sRow[2][tid] = (iF < Tn) ? iF : -1;
    }
    __syncthreads();

    const int srow = tid >> 2;            // 0..63 (rows srow, srow+64)
    const int schunk = (tid & 3) * 8;     // u16 offset within 32
    const u16* xTb = xT + (size_t)b * Tn * Cn;

    const u16 *pr0[3], *pr1[3];
    #pragma unroll
    for (int s = 0; s < 3; ++s) {
        int r0 = sRow[s][srow], r1 = sRow[s][srow + 64];
        pr0[s] = (r0 >= 0) ? (xTb + (size_t)r0 * Cn + schunk) : (zrow + schunk);
        pr1[s] = (r1 >= 0) ? (xTb + (size_t)r1 * Cn + schunk) : (zrow + schunk);
    }
    const u16* wbase = Wl + (size_t)(o0 + srow) * Kc + schunk;

    const int lane = tid & 63, wv = tid >> 6;
    const int wm = (wv & 1) * 64;   // t-half
    const int wn = (wv >> 1) * 64;  // o-half
    const int lr = lane & 15, quad = lane >> 4;

    const int ldsW = srow * 32 + schunk;          // this thread's DMA slot
    const int ldsW2 = (srow + 64) * 32 + schunk;

    auto dma = [&](int kg, int bsel) {
        int seg = kg >> 3, kk = (kg & 7) * 32;
        u16* bx = smem + bsel * 4096;
        u16* bw = smem + 8192 + bsel * 4096;
        g2l16(wbase + seg * 256 + kk,                 bw + ldsW);
        g2l16(wbase + (size_t)64 * Kc + seg * 256 + kk, bw + ldsW2);
        g2l16(pr0[seg] + kk, bx + ldsW);
        g2l16(pr1[seg] + kk, bx + ldsW2);
    };

    f32x4 acc[4][4] = {};
    dma(0, 0);

    #pragma unroll
    for (int kg = 0; kg < 24; ++kg) {
        __syncthreads();                 // chunk kg ready; prev reads done
        if (kg + 1 < 24) dma(kg + 1, (kg + 1) & 1);
        const u16* bX = smem + (kg & 1) * 4096;
        const u16* bW = smem + 8192 + (kg & 1) * 4096;

        bf8 af[4], bg[4];
        #pragma unroll
        for (int mi = 0; mi < 4; ++mi)
            af[mi] = *(const bf8*)(bX + (wm + mi * 16 + lr) * 32 + quad * 8);
        #pragma unroll
        for (int ni = 0; ni < 4; ++ni)
            bg[ni] = *(const bf8*)(bW + (wn + ni * 16 + lr) * 32 + quad * 8);
        #pragma unroll
        for (int mi = 0; mi < 4; ++mi)
            #pragma unroll
            for (int ni = 0; ni < 4; ++ni)
                acc[mi][ni] = __builtin_amdgcn_mfma_f32_16x16x32_bf16(
                    af[mi], bg[ni], acc[mi][ni], 0, 0, 0);
    }

    // epilogue: D row = m = t (quad*4+r), col = n = o (lr)
    float bias[4];
    #pragma unroll
    for (int ni = 0; ni < 4; ++ni) bias[ni] = bS[o0 + wn + ni * 16 + lr];
    u16* zTb = zT + (size_t)b * Tn * Cn;
    #pragma unroll
    for (int mi = 0; mi < 4; ++mi)
        #pragma unroll
        for (int r = 0; r < 4; ++r) {
            int t = t0 + wm + mi * 16 + quad * 4 + r;
            u16* row = zTb + (size_t)t * Cn + o0 + wn;
            #pragma unroll
            for (int ni = 0; ni < 4; ++ni)
                row[ni * 16 + lr] = f2bf(lrelu(acc[mi][ni][r] + bias[ni]));
        }
}

// ---------------------------------------------------------------------------
// GEMM2 (conv3 + residual + fused next-layer prep):
//   out[b][o][t] = sum_{tap,c} WAp[o][tap*256+c]*zT[t+tap-1][c] + bA[o] + xres
//   if writeXT: xTn[b][t][o] = bf16(lrelu(out))  (per-wave LDS transpose)
//   A = W (m=o), B = Z (n=t). Same double-buffered pipeline.
// ---------------------------------------------------------------------------
__global__ __launch_bounds__(256)
void k_gemm2(const u16* __restrict__ zT, const u16* __restrict__ WAl,
             const float* __restrict__ bA, const float* __restrict__ xres,
             float* __restrict__ out, u16* __restrict__ xTn, int writeXT,
             const u16* __restrict__ zrow)
{
    __shared__ u16 smem[4 * 4096];   // [sZ0][sZ1][sW0][sW1]; reused by epilogue

    const int tid = threadIdx.x;
    const int b = blockIdx.z;
    const int t0 = blockIdx.x * 128;
    const int o0 = blockIdx.y * 128;

    const int srow = tid >> 2;
    const int schunk = (tid & 3) * 8;
    const int lane = tid & 63, wv = tid >> 6;
    const int wo = (wv & 1) * 64;   // o-half (m)
    const int wt = (wv >> 1) * 64;  // t-half (n)
    const int lr = lane & 15, quad = lane >> 4;

    const u16* zTb = zT + (size_t)b * Tn * Cn;
    const u16 *zr0[3], *zr1[3];
    #pragma unroll
    for (int tap = 0; tap < 3; ++tap) {
        int r0 = t0 + srow + tap - 1;
        int r1 = r0 + 64;
        zr0[tap] = (r0 >= 0 && r0 < Tn) ? (zTb + (size_t)r0 * Cn + schunk)
                                        : (zrow + schunk);
        zr1[tap] = (r1 >= 0 && r1 < Tn) ? (zTb + (size_t)r1 * Cn + schunk)
                                        : (zrow + schunk);
    }
    const u16* wbase = WAl + (size_t)(o0 + srow) * Kc + schunk;

    const int ldsW = srow * 32 + schunk;
    const int ldsW2 = (srow + 64) * 32 + schunk;

    auto dma = [&](int kg, int bsel) {
        int tap = kg >> 3, kk = (kg & 7) * 32;
        u16* bz = smem + bsel * 4096;
        u16* bw = smem + 8192 + bsel * 4096;
        g2l16(wbase + tap * 256 + kk,                   bw + ldsW);
        g2l16(wbase + (size_t)64 * Kc + tap * 256 + kk, bw + ldsW2);
        g2l16(zr0[tap] + kk, bz + ldsW);
        g2l16(zr1[tap] + kk, bz + ldsW2);
    };

    f32x4 acc[4][4] = {};
    dma(0, 0);

    #pragma unroll
    for (int kg = 0; kg < 24; ++kg) {
        __syncthreads();
        if (kg + 1 < 24) dma(kg + 1, (kg + 1) & 1);
        const u16* bZ = smem + (kg & 1) * 4096;
        const u16* bW = smem + 8192 + (kg & 1) * 4096;

        bf8 af[4], bg[4];
        #pragma unroll
        for (int mi = 0; mi < 4; ++mi)
            af[mi] = *(const bf8*)(bW + (wo + mi * 16 + lr) * 32 + quad * 8);
        #pragma unroll
        for (int ni = 0; ni < 4; ++ni)
            bg[ni] = *(const bf8*)(bZ + (wt + ni * 16 + lr) * 32 + quad * 8);
        #pragma unroll
        for (int mi = 0; mi < 4; ++mi)
            #pragma unroll
            for (int ni = 0; ni < 4; ++ni)
                acc[mi][ni] = __builtin_amdgcn_mfma_f32_16x16x32_bf16(
                    af[mi], bg[ni], acc[mi][ni], 0, 0, 0);
    }

    float biasv[4][4];
    #pragma unroll
    for (int mi = 0; mi < 4; ++mi) {
        float4 bb = *(const float4*)(bA + o0 + wo + mi * 16 + quad * 4);
        biasv[mi][0] = bb.x; biasv[mi][1] = bb.y; biasv[mi][2] = bb.z; biasv[mi][3] = bb.w;
    }

    if (writeXT) {
        // per-wave 16t x 64o strips, padded rows (72 u16 = 144B)
        u16* strip = smem + wv * 1152;
        u16* xTb2 = xTn + (size_t)b * Tn * Cn;
        #pragma unroll
        for (int ni = 0; ni < 4; ++ni) {
            __syncthreads();   // staging/strip LDS free of readers
            #pragma unroll
            for (int mi = 0; mi < 4; ++mi) {
                ushort4 pk;
                #pragma unroll
                for (int r = 0; r < 4; ++r) {
                    int o = o0 + wo + mi * 16 + quad * 4 + r;
                    size_t idx = ((size_t)b * Cn + o) * Tn + t0 + wt + ni * 16 + lr;
                    float v = acc[mi][ni][r] + biasv[mi][r] + xres[idx];
                    out[idx] = v;
                    ((u16*)&pk)[r] = f2bf(lrelu(v));
                }
                *(ushort4*)(strip + lr * 72 + mi * 16 + quad * 4) = pk;
            }
            __syncthreads();   // strip writes visible
            #pragma unroll
            for (int it = 0; it < 2; ++it) {
                int tt = (lane >> 3) + it * 8;
                uint4 vv = *(const uint4*)(strip + tt * 72 + (lane & 7) * 8);
                *(uint4*)(xTb2 + (size_t)(t0 + wt + ni * 16 + tt) * Cn
                          + o0 + wo + (lane & 7) * 8) = vv;
            }
        }
    } else {
        #pragma unroll
        for (int mi = 0; mi < 4; ++mi)
            #pragma unroll
            for (int r = 0; r < 4; ++r) {
                int o = o0 + wo + mi * 16 + quad * 4 + r;
                size_t base = ((size_t)b * Cn + o) * Tn + t0 + wt;
                #pragma unroll
                for (int ni = 0; ni < 4; ++ni) {
                    size_t idx = base + ni * 16 + lr;
                    out[idx] = acc[mi][ni][r] + biasv[mi][r] + xres[idx];
                }
            }
    }
}

extern "C" void kernel_launch(void* const* d_in, const int* in_sizes, int n_in,
                              void* d_out, int out_size, void* d_ws, size_t ws_size,
                              hipStream_t stream)
{
    const float* x  = (const float*)d_in[0];
    const float* d  = (const float*)d_in[1];
    const float* WC = (const float*)d_in[2];
    const float* bC = (const float*)d_in[3];
    const float* WP = (const float*)d_in[4];
    const float* bP = (const float*)d_in[5];
    const float* WF = (const float*)d_in[6];
    const float* bF = (const float*)d_in[7];
    const float* WA = (const float*)d_in[8];
    const float* bA = (const float*)d_in[9];
    float* out = (float*)d_out;

    char* ws = (char*)d_ws;
    u16*   xT   = (u16*)(ws);                                   // 32 MiB
    u16*   zT   = (u16*)(ws + (size_t)Bn * Tn * Cn * 2);        // 32 MiB
    u16*   Wcat = (u16*)(ws + (size_t)2 * Bn * Tn * Cn * 2);    // 1.125 MiB
    u16*   WAp  = Wcat + (size_t)NL * Cn * Kc;                  // 1.125 MiB
    float* bSum = (float*)(WAp + (size_t)NL * Cn * Kc);         // 3 KiB
    u16*   zrow = (u16*)(bSum + NL * Cn);                       // 512 B zero row

    k_wprep<<<dim3(1024), dim3(256), 0, stream>>>(WC, WP, WF, WA, bC, bP, bF,
                                                  Wcat, WAp, bSum, zrow);

    dim3 gP(Tn / 64, Cn / 64, Bn);      // prep: 128 x 4 x 8
    dim3 gG(Tn / 128, Cn / 128, Bn);    // gemms: 64 x 2 x 8
    dim3 blk(256);

    k_prep<<<gP, blk, 0, stream>>>(x, xT);   // layer-0 input only

    const float dils[NL] = {1.f, 2.f, 4.f};
    const float* xcur = x;
    for (int i = 0; i < NL; ++i) {
        k_gemm1<<<gG, blk, 0, stream>>>(xT, d,
                                        Wcat + (size_t)i * Cn * Kc,
                                        bSum + (size_t)i * Cn,
                                        dils[i], zT, zrow);
        k_gemm2<<<gG, blk, 0, stream>>>(zT,
                                        WAp + (size_t)i * Cn * Kc,
                                        bA + (size_t)i * Cn,
                                        xcur, out, xT, (i < NL - 1) ? 1 : 0,
                                        zrow);
        xcur = out;   // residual read-then-write same element: in-place safe
    }
}